// Round 12
// baseline (110.304 us; speedup 1.0000x reference)
//
#include <hip/hip_runtime.h>
#include <math.h>

#define N 8192
#define FIN 256
#define FOUT 64
#define ALPHA 0.2f
#define LOG2E 1.442695040888963f

#define NTH 16                    // tiles per j-half (4096/256)
#define ABUF 8192                 // 16 rows * 512 B
#define SMEM_BYTES (2 * ABUF)     // 16 KB

typedef float f32x4 __attribute__((ext_vector_type(4)));
typedef _Float16 f16x8 __attribute__((ext_vector_type(8)));

union F16V { uint4 u; f16x8 h; };

__device__ __forceinline__ unsigned pack_f16(float a, float b) {
    union { _Float16 h; unsigned short u; } ca, cb;
    ca.h = (_Float16)a; cb.h = (_Float16)b;      // v_cvt_f16_f32, RNE
    return (unsigned)ca.u | ((unsigned)cb.u << 16);
}
// w' = exp(leaky(e)) * 2^-4  (scale cancels in softmax ratio; keeps f16 in range)
__device__ __forceinline__ float wcalc(int av, float fsr, float g) {
    float e = fsr + g;
    float le = e > 0.f ? e : ALPHA * e;
    float r = __builtin_exp2f(fmaf(le, LOG2E, -4.0f));
    return av != 0 ? r : 0.f;
}

// ---------------- Kernel 1: Wh = h@W -> fsrc/fdst + B_packed (pre-fragmented f16) ----
// Bp[(chunk*4+ft)*64 + lane] = f16(Wh[chunk*32+(lane>>4)*8+e][ft*16+(lane&15)])
__global__ __launch_bounds__(512) void gat_prep(
    const float* __restrict__ h, const float* __restrict__ W,
    const float* __restrict__ a,
    float* __restrict__ fsrc, float* __restrict__ fdst,
    uint4* __restrict__ Bp)
{
    __shared__ float sWh[32][FOUT + 1];
    const int t = threadIdx.x;
    const int f = t & 63;
    const int wq = t >> 6;
    const int row0 = blockIdx.x * 32;
    const int rbase = row0 + wq * 4;

    float acc[4] = {0.f, 0.f, 0.f, 0.f};
    for (int k0 = 0; k0 < FIN; k0 += 4) {
        const float w0 = W[(k0 + 0) * FOUT + f];
        const float w1 = W[(k0 + 1) * FOUT + f];
        const float w2 = W[(k0 + 2) * FOUT + f];
        const float w3 = W[(k0 + 3) * FOUT + f];
#pragma unroll
        for (int rr = 0; rr < 4; ++rr) {
            const float4 hv = *reinterpret_cast<const float4*>(
                &h[(size_t)(rbase + rr) * FIN + k0]);
            acc[rr] = fmaf(hv.x, w0, acc[rr]);
            acc[rr] = fmaf(hv.y, w1, acc[rr]);
            acc[rr] = fmaf(hv.z, w2, acc[rr]);
            acc[rr] = fmaf(hv.w, w3, acc[rr]);
        }
    }
    const float as = a[f], ad = a[FOUT + f];
#pragma unroll
    for (int rr = 0; rr < 4; ++rr) {
        sWh[wq * 4 + rr][f] = acc[rr];
        float fs = acc[rr] * as, fd = acc[rr] * ad;
#pragma unroll
        for (int off = 1; off < 64; off <<= 1) {
            fs += __shfl_xor(fs, off, 64);
            fd += __shfl_xor(fd, off, 64);
        }
        if (f == 0) { fsrc[rbase + rr] = fs; fdst[rbase + rr] = fd; }
    }
    __syncthreads();
    if (t < 256) {
        const int ft = t >> 6;
        const int l = t & 63;
        const int li = l & 15, g = l >> 4;
        float v[8];
#pragma unroll
        for (int e = 0; e < 8; ++e) v[e] = sWh[g * 8 + e][ft * 16 + li];
        uint4 pk;
        pk.x = pack_f16(v[0], v[1]);
        pk.y = pack_f16(v[2], v[3]);
        pk.z = pack_f16(v[4], v[5]);
        pk.w = pack_f16(v[6], v[7]);
        Bp[(size_t)(blockIdx.x * 4 + ft) * 64 + l] = pk;
    }
}

// ---------------- Kernel 2: 4-wave j-split MFMA flash softmax-PV (partials) ----
// 1024 blocks: (row-tile rt = bid>>1) x (j-half hf = bid&1), 16 rows x 4096 cols.
// 4 waves = ft quadrants; each wave does ALL 8 k-slots -> complete 16-col output
// quadrant per wave (no cross-wave acc reduce). 4 blocks/CU = 4 independent
// barrier groups per SIMD. Counted-vmcnt FIFO: STAGE waits AG (B in flight),
// MFMA waits B (AG(t+1) in flight); BAR drains lgkm only.
__global__ __launch_bounds__(256, 4) void gat_main(
    const int* __restrict__ adj,
    const uint4* __restrict__ Bp,
    const float* __restrict__ fsrc, const float* __restrict__ fdst,
    f32x4* __restrict__ pacc, float* __restrict__ pz)
{
    __shared__ __align__(16) char smem[SMEM_BYTES];

    const int t = threadIdx.x;
    const int l = t & 63;
    const int w = t >> 6;                  // ft quadrant
    const int rt = blockIdx.x >> 1;
    const int hf = blockIdx.x & 1;
    const int row0 = rt * 16;
    const int jbase = hf * 4096;

    // --- staging map: thread -> (row srow, 16 cols at scol) ---
    const int srow = t >> 4;               // 0..15
    const int scol = (t & 15) * 16;
    const float fsr = fsrc[row0 + srow];
    const size_t adjrow = (size_t)(row0 + srow) * N + jbase;
    const int swz = (srow & 7) << 4;
    const int awo0 = srow * 512 + ((scol * 2) ^ swz);
    const int awo1 = srow * 512 + ((scol * 2 + 16) ^ swz);

    // --- MFMA map ---
    const int r16 = l & 15;
    const int kg8 = (l >> 4) << 3;
    const int fswz = (r16 & 7) << 4;
    const int aro = r16 * 512;
    // Bp uint4 index: (tileg*8+ks)*256... = tileg*2048 + ks*256 + ft*64 + lane
    const uint4* Bq = Bp + (size_t)hf * 16 * 2048 + w * 64 + l;

    f32x4 acc = {0.f, 0.f, 0.f, 0.f};
    float zacc = 0.f;
    int4 A0, A1, A2, A3; float4 G0, G1, G2, G3;
    uint4 B0, B1, B2, B3, B4, B5, B6, B7;

#define BAR                                                                    \
    {                                                                          \
        asm volatile("s_waitcnt lgkmcnt(0)" ::: "memory");                     \
        __builtin_amdgcn_s_barrier();                                          \
    }

#define LOAD_ADJG(tile)                                                        \
    {                                                                          \
        const size_t o_ = adjrow + (tile) * 256 + scol;                        \
        A0 = *reinterpret_cast<const int4*>(&adj[o_]);                         \
        A1 = *reinterpret_cast<const int4*>(&adj[o_ + 4]);                     \
        A2 = *reinterpret_cast<const int4*>(&adj[o_ + 8]);                     \
        A3 = *reinterpret_cast<const int4*>(&adj[o_ + 12]);                    \
        const int g_ = jbase + (tile) * 256 + scol;                            \
        G0 = *reinterpret_cast<const float4*>(&fdst[g_]);                      \
        G1 = *reinterpret_cast<const float4*>(&fdst[g_ + 4]);                  \
        G2 = *reinterpret_cast<const float4*>(&fdst[g_ + 8]);                  \
        G3 = *reinterpret_cast<const float4*>(&fdst[g_ + 12]);                 \
    }

#define LOAD_B(tile)                                                           \
    {                                                                          \
        const uint4* bq_ = Bq + (size_t)(tile) * 2048;                         \
        B0 = bq_[0];    B1 = bq_[256];  B2 = bq_[512];  B3 = bq_[768];         \
        B4 = bq_[1024]; B5 = bq_[1280]; B6 = bq_[1536]; B7 = bq_[1792];        \
    }

#define STAGE(BUF)                                                             \
    {                                                                          \
        float wv[16];                                                          \
        wv[0] = wcalc(A0.x, fsr, G0.x);  wv[1] = wcalc(A0.y, fsr, G0.y);       \
        wv[2] = wcalc(A0.z, fsr, G0.z);  wv[3] = wcalc(A0.w, fsr, G0.w);       \
        wv[4] = wcalc(A1.x, fsr, G1.x);  wv[5] = wcalc(A1.y, fsr, G1.y);       \
        wv[6] = wcalc(A1.z, fsr, G1.z);  wv[7] = wcalc(A1.w, fsr, G1.w);       \
        wv[8] = wcalc(A2.x, fsr, G2.x);  wv[9] = wcalc(A2.y, fsr, G2.y);       \
        wv[10] = wcalc(A2.z, fsr, G2.z); wv[11] = wcalc(A2.w, fsr, G2.w);      \
        wv[12] = wcalc(A3.x, fsr, G3.x); wv[13] = wcalc(A3.y, fsr, G3.y);      \
        wv[14] = wcalc(A3.z, fsr, G3.z); wv[15] = wcalc(A3.w, fsr, G3.w);      \
        zacc += ((wv[0]+wv[1])+(wv[2]+wv[3])) + ((wv[4]+wv[5])+(wv[6]+wv[7]))  \
              + ((wv[8]+wv[9])+(wv[10]+wv[11]))+((wv[12]+wv[13])+(wv[14]+wv[15])); \
        uint4 p0, p1;                                                          \
        p0.x = pack_f16(wv[0], wv[1]);   p0.y = pack_f16(wv[2], wv[3]);        \
        p0.z = pack_f16(wv[4], wv[5]);   p0.w = pack_f16(wv[6], wv[7]);        \
        p1.x = pack_f16(wv[8], wv[9]);   p1.y = pack_f16(wv[10], wv[11]);      \
        p1.z = pack_f16(wv[12], wv[13]); p1.w = pack_f16(wv[14], wv[15]);      \
        *reinterpret_cast<uint4*>(smem + (BUF) * ABUF + awo0) = p0;            \
        *reinterpret_cast<uint4*>(smem + (BUF) * ABUF + awo1) = p1;            \
    }

#define MFMA_PHASE(BUF)                                                        \
    {                                                                          \
        const char* ab_ = smem + (BUF) * ABUF + aro;                           \
        __builtin_amdgcn_s_setprio(1);                                         \
        F16V a_, b_;                                                           \
        a_.u = *reinterpret_cast<const uint4*>(ab_ + (((0*32 + kg8) * 2) ^ fswz)); \
        b_.u = B0; acc = __builtin_amdgcn_mfma_f32_16x16x32_f16(a_.h, b_.h, acc, 0, 0, 0); \
        a_.u = *reinterpret_cast<const uint4*>(ab_ + (((1*32 + kg8) * 2) ^ fswz)); \
        b_.u = B1; acc = __builtin_amdgcn_mfma_f32_16x16x32_f16(a_.h, b_.h, acc, 0, 0, 0); \
        a_.u = *reinterpret_cast<const uint4*>(ab_ + (((2*32 + kg8) * 2) ^ fswz)); \
        b_.u = B2; acc = __builtin_amdgcn_mfma_f32_16x16x32_f16(a_.h, b_.h, acc, 0, 0, 0); \
        a_.u = *reinterpret_cast<const uint4*>(ab_ + (((3*32 + kg8) * 2) ^ fswz)); \
        b_.u = B3; acc = __builtin_amdgcn_mfma_f32_16x16x32_f16(a_.h, b_.h, acc, 0, 0, 0); \
        a_.u = *reinterpret_cast<const uint4*>(ab_ + (((4*32 + kg8) * 2) ^ fswz)); \
        b_.u = B4; acc = __builtin_amdgcn_mfma_f32_16x16x32_f16(a_.h, b_.h, acc, 0, 0, 0); \
        a_.u = *reinterpret_cast<const uint4*>(ab_ + (((5*32 + kg8) * 2) ^ fswz)); \
        b_.u = B5; acc = __builtin_amdgcn_mfma_f32_16x16x32_f16(a_.h, b_.h, acc, 0, 0, 0); \
        a_.u = *reinterpret_cast<const uint4*>(ab_ + (((6*32 + kg8) * 2) ^ fswz)); \
        b_.u = B6; acc = __builtin_amdgcn_mfma_f32_16x16x32_f16(a_.h, b_.h, acc, 0, 0, 0); \
        a_.u = *reinterpret_cast<const uint4*>(ab_ + (((7*32 + kg8) * 2) ^ fswz)); \
        b_.u = B7; acc = __builtin_amdgcn_mfma_f32_16x16x32_f16(a_.h, b_.h, acc, 0, 0, 0); \
        __builtin_amdgcn_s_setprio(0);                                         \
    }

    // ---- prologue (FIFO: AG(0), B(0)) ----
    LOAD_ADJG(0);
    LOAD_B(0);

    for (int tt = 0; tt < NTH; tt += 2) {
        // even tile tt -> buf0
        STAGE(0);                              // waits AG(tt): vmcnt(8), B in flight
        LOAD_ADJG(tt + 1);
        BAR;
        MFMA_PHASE(0);                         // waits B(tt): vmcnt(8), AG(tt+1) in flight
        LOAD_B(tt + 1);
        // odd tile tt+1 -> buf1
        STAGE(1);
        if (tt + 2 < NTH) LOAD_ADJG(tt + 2);
        BAR;
        MFMA_PHASE(1);
        if (tt + 2 < NTH) LOAD_B(tt + 2);
    }
#undef LOAD_ADJG
#undef LOAD_B
#undef STAGE
#undef MFMA_PHASE
#undef BAR

    // ---- per-block partials: Z row-sums + raw acc (no division here) ----
    {
        float z = zacc;
        z += __shfl_xor(z, 1, 64);
        z += __shfl_xor(z, 2, 64);
        z += __shfl_xor(z, 4, 64);
        z += __shfl_xor(z, 8, 64);
        if ((t & 15) == 0) pz[blockIdx.x * 16 + srow] = z;
    }
    pacc[(size_t)blockIdx.x * 256 + t] = acc;
}

// ---------------- Kernel 3: combine j-halves + softmax divide + ELU ----
__global__ __launch_bounds__(256) void gat_reduce(
    const float* __restrict__ pacc, const float* __restrict__ pz,
    float* __restrict__ out)
{
    const int e = blockIdx.x * 256 + threadIdx.x;    // 0..524287
    const int rt = e >> 10;
    const int wi = e & 1023;
    const int row = wi >> 6;
    const int col = wi & 63;
    // inverse of gat_main's (wave ft, lane, reg) -> (row, col) mapping
    const int idx = ((col >> 4) << 8) + ((row >> 2) << 6) + ((col & 15) << 2) + (row & 3);
    const float s = pacc[(size_t)(rt * 2) * 1024 + idx] +
                    pacc[(size_t)(rt * 2 + 1) * 1024 + idx];
    const float z = pz[(rt * 2) * 16 + row] + pz[(rt * 2 + 1) * 16 + row];
    const float hp = s / z;
    out[(size_t)(rt * 16 + row) * 64 + col] = hp > 0.f ? hp : expm1f(hp);
}

extern "C" void kernel_launch(void* const* d_in, const int* in_sizes, int n_in,
                              void* d_out, int out_size, void* d_ws, size_t ws_size,
                              hipStream_t stream) {
    const float* h   = (const float*)d_in[0];
    const int*   adj = (const int*)d_in[1];
    const float* W   = (const float*)d_in[2];
    const float* a   = (const float*)d_in[3];
    float* out = (float*)d_out;

    float* ws = (float*)d_ws;
    float* fsrc = ws;                              // 8192
    float* fdst = fsrc + N;                        // 8192
    uint4* Bp = (uint4*)(fdst + N);                // 65536 uint4 = 1 MB
    float* paccf = (float*)(Bp + 65536);           // 1024*1024 f32 = 4 MB
    float* pz = paccf + 1024 * 1024;               // 16384 f32

    gat_prep<<<dim3(N / 32), dim3(512), 0, stream>>>(h, W, a, fsrc, fdst, Bp);
    gat_main<<<dim3(1024), dim3(256), 0, stream>>>(
        adj, Bp, fsrc, fdst, (f32x4*)paccf, pz);
    gat_reduce<<<dim3(2048), dim3(256), 0, stream>>>(paccf, pz, out);
}